// Round 20
// baseline (74.188 us; speedup 1.0000x reference)
//
#include <hip/hip_runtime.h>

#define N_TOT 4096
#define N_HALF 2048
#define DIMS 64
#define BATCH 4
#define WGRID 64               // 4096/64 wave-tile rows
#define TRI_PER_BATCH 2080     // 64*65/2 upper-tri 64x64 wave-tiles
#define NJOB_PER_BATCH 1056    // sum over rows of ceil((64-ib)/2) tile-pairs
#define NJOB (BATCH * NJOB_PER_BATCH)   // 4224, divisible by 8

typedef __attribute__((ext_vector_type(8))) short short8;
typedef __attribute__((ext_vector_type(4))) float f32x4;

#if __has_builtin(__builtin_amdgcn_exp2f)
#define EXP2F(x) __builtin_amdgcn_exp2f(x)
#else
#define EXP2F(x) exp2f(x)
#endif

__device__ __forceinline__ unsigned short f2bf_rne(float f) {
    unsigned int u = __float_as_uint(f);
    unsigned int r = (u + 0x7FFFu + ((u >> 16) & 1u)) >> 16;
    return (unsigned short)r;
}
__device__ __forceinline__ float bf2f(unsigned short h) {
    return __uint_as_float(((unsigned int)h) << 16);
}

// Prep: fp32 -> bf16 hi/lo split, row sq-norms, per-block partials for Ssq and
// colsum. 256 blocks x 256 thr x 16 floats. (r14/r18 version, unchanged)
__global__ __launch_bounds__(256) void prep_kernel(const float* __restrict__ x,
                                                   const float* __restrict__ y,
                                                   unsigned short* __restrict__ hi,
                                                   unsigned short* __restrict__ lo,
                                                   float* __restrict__ sq,
                                                   float* __restrict__ ssq_part,
                                                   float* __restrict__ colsum_part) {
    int g = blockIdx.x;
    int t = threadIdx.x;
    bool isx = g < 128;
    int gg = isx ? g : g - 128;
    int base = gg << 12;
    int b = gg >> 5;
    const float* src = isx ? x : y;

    float q_acc = 0.f;
    float4 c_acc = {0.f, 0.f, 0.f, 0.f};
#pragma unroll
    for (int it = 0; it < 4; ++it) {
        int e = base + (it << 10) + (t << 2);
        int rem = e & 131071;
        float4 v = *(const float4*)(src + e);
        unsigned dst = (unsigned)b * 262144u + (isx ? 0u : 131072u) + (unsigned)rem;
        ushort4 h, l;
        h.x = f2bf_rne(v.x); l.x = f2bf_rne(v.x - bf2f(h.x));
        h.y = f2bf_rne(v.y); l.y = f2bf_rne(v.y - bf2f(h.y));
        h.z = f2bf_rne(v.z); l.z = f2bf_rne(v.z - bf2f(h.z));
        h.w = f2bf_rne(v.w); l.w = f2bf_rne(v.w - bf2f(h.w));
        *(ushort4*)(hi + dst) = h;
        *(ushort4*)(lo + dst) = l;

        float p = fmaf(v.x, v.x, fmaf(v.y, v.y, fmaf(v.z, v.z, v.w * v.w)));
        p += __shfl_xor(p, 1);
        p += __shfl_xor(p, 2);
        p += __shfl_xor(p, 4);
        p += __shfl_xor(p, 8);
        int rwi = rem >> 6;
        if ((t & 15) == 0)
            sq[b * N_TOT + (isx ? rwi : N_HALF + rwi)] = p;

        float q = p;
        q += __shfl_xor(q, 16);
        q += __shfl_xor(q, 32);
        q_acc += q;

        float4 c = v;
        c.x += __shfl_xor(c.x, 16); c.y += __shfl_xor(c.y, 16);
        c.z += __shfl_xor(c.z, 16); c.w += __shfl_xor(c.w, 16);
        c.x += __shfl_xor(c.x, 32); c.y += __shfl_xor(c.y, 32);
        c.z += __shfl_xor(c.z, 32); c.w += __shfl_xor(c.w, 32);
        c_acc.x += c.x; c_acc.y += c.y; c_acc.z += c.z; c_acc.w += c.w;
    }

    __shared__ float wsum[4];
    __shared__ float4 csh[4][16];
    int wid = t >> 6;
    if ((t & 63) == 0) wsum[wid] = q_acc;
    if ((t & 63) < 16) csh[wid][t & 63] = c_acc;
    __syncthreads();
    if (t == 0) ssq_part[g] = wsum[0] + wsum[1] + wsum[2] + wsum[3];
    if (t < 16) {
        float4 s0 = csh[0][t], s1 = csh[1][t], s2 = csh[2][t], s3 = csh[3][t];
        float4 o;
        o.x = s0.x + s1.x + s2.x + s3.x;
        o.y = s0.y + s1.y + s2.y + s3.y;
        o.z = s0.z + s1.z + s2.z + s3.z;
        o.w = s0.w + s1.w + s2.w + s3.w;
        *(float4*)(colsum_part + (size_t)g * 64 + t * 4) = o;
    }
}

// Reduce partials -> k0[b]. 4 blocks (one per batch). (unchanged)
__global__ __launch_bounds__(256) void bw_kernel(const float* __restrict__ ssq_part,
                                                 const float* __restrict__ colsum_part,
                                                 float* __restrict__ k0arr) {
    int b = blockIdx.x;
    int t = threadIdx.x;
    int c = t & 63, q = t >> 6;
    float cs = 0.f;
#pragma unroll
    for (int pp = 0; pp < 16; ++pp) {
        int p = q * 16 + pp;
        int g = (p < 32) ? (b * 32 + p) : (128 + b * 32 + (p - 32));
        cs += colsum_part[(size_t)g * 64 + c];
    }
    __shared__ float csq[4][64];
    csq[q][c] = cs;
    __syncthreads();
    if (t < 64) {
        float col = csq[0][t] + csq[1][t] + csq[2][t] + csq[3][t];
        double cc = (double)col * (double)col;
#pragma unroll
        for (int o = 32; o > 0; o >>= 1) cc += __shfl_xor(cc, o);
        int g = (t < 32) ? (b * 32 + t) : (128 + b * 32 + (t - 32));
        double sd = (double)ssq_part[g];
#pragma unroll
        for (int o = 32; o > 0; o >>= 1) sd += __shfl_xor(sd, o);
        if (t == 0) {
            double sumL2 = 2.0 * (double)N_TOT * sd - 2.0 * cc;
            double bw = sumL2 / ((double)N_TOT * (double)N_TOT - (double)N_TOT);
            bw *= 0.25;
            k0arr[b] = (float)(-1.4426950408889634 / bw);
        }
    }
}

// Pair body macro: per mf, load the A row ONCE and feed BOTH tiles' quadrants.
// All locals register-resident (r16 lesson: no pointer-passed arrays).
// Tile A may be diagonal (compile-time DIAGA); tile B never is.
#define MMD_PAIR_BODY(DIAGA)                                                   \
    _Pragma("unroll")                                                          \
    for (int mf = 0; mf < 4; ++mf) {                                           \
        unsigned ra = (i0 + (unsigned)mf * 16u + lrow) * 64u + kbase;          \
        short8 ah0 = *(const short8*)(Hb + ra);                                \
        short8 ah1 = *(const short8*)(Hb + ra + 32u);                          \
        short8 al0 = *(const short8*)(Lb + ra);                                \
        short8 al1 = *(const short8*)(Lb + ra + 32u);                          \
        float4 sv = *(const float4*)(sqb + i0 + (unsigned)mf * 16u + rquad);   \
        float ki0 = k16 * sv.x, ki1 = k16 * sv.y;                              \
        float ki2 = k16 * sv.z, ki3 = k16 * sv.w;                              \
        _Pragma("unroll")                                                      \
        for (int nf = 0; nf < 4; ++nf) {                                       \
            const short* bp = B0A + (nf * 16 + (int)lrow) * 8;                 \
            short8 bh0 = *(const short8*)(bp);                                 \
            short8 bh1 = *(const short8*)(bp + 2048);                          \
            f32x4 accP = (f32x4){0.f, 0.f, 0.f, 0.f};                          \
            f32x4 accQ = (f32x4){0.f, 0.f, 0.f, 0.f};                          \
            accP = __builtin_amdgcn_mfma_f32_16x16x32_bf16(ah0, bh0, accP, 0, 0, 0); \
            accQ = __builtin_amdgcn_mfma_f32_16x16x32_bf16(ah1, bh1, accQ, 0, 0, 0); \
            accP = __builtin_amdgcn_mfma_f32_16x16x32_bf16(al0, bh0, accP, 0, 0, 0); \
            accQ = __builtin_amdgcn_mfma_f32_16x16x32_bf16(al1, bh1, accQ, 0, 0, 0); \
            float kjn = (nf == 0) ? kjA0 : (nf == 1) ? kjA1 : (nf == 2) ? kjA2 : kjA3; \
            _Pragma("unroll")                                                  \
            for (int rg = 0; rg < 4; ++rg) {                                   \
                float kir = (rg == 0) ? ki0 : (rg == 1) ? ki1 : (rg == 2) ? ki2 : ki3; \
                float t16 = fmaf(m2k16, accQ[rg], fmaf(m2k16, accP[rg], kir + kjn)); \
                float e4 = EXP2F(t16);                                         \
                float e3 = e4 * e4;                                            \
                float e2 = e3 * e3;                                            \
                float e1 = e2 * e2;                                            \
                float e0 = e1 * e1;                                            \
                float es = ((e0 + e1) + (e2 + e3)) + e4;                       \
                if (DIAGA) {                                                   \
                    int i = mf * 16 + (int)rquad + rg;                         \
                    int j = nf * 16 + (int)lrow;                               \
                    float w = (j > i) ? 2.f : ((j == i) ? 1.f : 0.f);          \
                    es *= w;                                                   \
                }                                                              \
                if (rg & 1) eaccA1 += es; else eaccA0 += es;                   \
            }                                                                  \
        }                                                                      \
        _Pragma("unroll")                                                      \
        for (int nf = 0; nf < 4; ++nf) {                                       \
            const short* bp = B0B + (nf * 16 + (int)lrow) * 8;                 \
            short8 bh0 = *(const short8*)(bp);                                 \
            short8 bh1 = *(const short8*)(bp + 2048);                          \
            f32x4 accP = (f32x4){0.f, 0.f, 0.f, 0.f};                          \
            f32x4 accQ = (f32x4){0.f, 0.f, 0.f, 0.f};                          \
            accP = __builtin_amdgcn_mfma_f32_16x16x32_bf16(ah0, bh0, accP, 0, 0, 0); \
            accQ = __builtin_amdgcn_mfma_f32_16x16x32_bf16(ah1, bh1, accQ, 0, 0, 0); \
            accP = __builtin_amdgcn_mfma_f32_16x16x32_bf16(al0, bh0, accP, 0, 0, 0); \
            accQ = __builtin_amdgcn_mfma_f32_16x16x32_bf16(al1, bh1, accQ, 0, 0, 0); \
            float kjn = (nf == 0) ? kjB0 : (nf == 1) ? kjB1 : (nf == 2) ? kjB2 : kjB3; \
            _Pragma("unroll")                                                  \
            for (int rg = 0; rg < 4; ++rg) {                                   \
                float kir = (rg == 0) ? ki0 : (rg == 1) ? ki1 : (rg == 2) ? ki2 : ki3; \
                float t16 = fmaf(m2k16, accQ[rg], fmaf(m2k16, accP[rg], kir + kjn)); \
                float e4 = EXP2F(t16);                                         \
                float e3 = e4 * e4;                                            \
                float e2 = e3 * e3;                                            \
                float e1 = e2 * e2;                                            \
                float e0 = e1 * e1;                                            \
                float es = ((e0 + e1) + (e2 + e3)) + e4;                       \
                if (rg & 1) eaccB1 += es; else eaccB0 += es;                   \
            }                                                                  \
        }                                                                      \
    }

// Main: SINGLE-WAVE blocks, each computing a PAIR of same-row 64x64 tiles
// (jb_rel = 2k, 2k+1). Their B panels are one contiguous 128-row span ->
// staged together (16 KB LDS, ONE staging drain for two tiles); each A row
// is loaded once and feeds both tiles (A traffic halved). Odd-length rows:
// the last job's tile B is clamped and weighted 0 (wave-uniform, ~3% waste).
__global__ void mmd_mfma(const unsigned short* __restrict__ hi,
                         const unsigned short* __restrict__ lo,
                         const float* __restrict__ sq,
                         const float* __restrict__ k0arr,
                         double* __restrict__ pblock) {
    // bijective XCD swizzle (NJOB % 8 == 0)
    int wg0 = blockIdx.x;
    int job = (wg0 & 7) * (NJOB / 8) + (wg0 >> 3);
    int b = job / NJOB_PER_BATCH;
    int r = job % NJOB_PER_BATCH;
    int ib = 0, cum = 0;
    while (r >= cum + ((65 - ib) >> 1)) { cum += (65 - ib) >> 1; ++ib; }
    int k = r - cum;                      // pair index within row ib
    int jbA = ib + 2 * k;                 // tile A column block (always valid)
    bool has2 = (ib + 2 * k + 1) < WGRID; // tile B exists
    int jbB = has2 ? (jbA + 1) : jbA;     // clamped when absent
    unsigned i0 = (unsigned)ib * 64u;
    unsigned j0A = (unsigned)jbA * 64u;
    unsigned j0B = (unsigned)jbB * 64u;
    int lane = threadIdx.x;               // 0..63

    const unsigned short* Hb = hi + (unsigned)b * 262144u;
    const unsigned short* Lb = lo + (unsigned)b * 262144u;
    const float* sqb = sq + b * N_TOT;

    // ---- stage both B-hi panels (2 x 64 rows x 64 k = 16 KB) ----
    // [panel][slot8][row64]: short idx = panel*4096 + slot*512 + row*8.
    __shared__ short ldsB[8192];
    {
        unsigned gbA = (j0A + (unsigned)lane) * 64u;
        unsigned gbB = (j0B + (unsigned)lane) * 64u;
#pragma unroll
        for (int kk = 0; kk < 8; ++kk) {
            short8 vA = *(const short8*)(Hb + gbA + (unsigned)kk * 8u);
            short8 vB = *(const short8*)(Hb + gbB + (unsigned)kk * 8u);
            *(short8*)(ldsB + kk * 512 + lane * 8) = vA;
            *(short8*)(ldsB + 4096 + kk * 512 + lane * 8) = vB;
        }
    }
    // no __syncthreads: single wave, ds_read ordered after ds_write by waitcnt.

    bool diagA = (k == 0);                // tile A is the diagonal tile
    float wsignA = ((i0 < (unsigned)N_HALF) == (j0A < (unsigned)N_HALF)) ? 1.f : -1.f;
    float wsignB = ((i0 < (unsigned)N_HALF) == (j0B < (unsigned)N_HALF)) ? 1.f : -1.f;
    float scaleA = diagA ? wsignA : 2.f * wsignA;
    float scaleB = has2 ? 2.f * wsignB : 0.f;

    float k16 = k0arr[b] * 0.0625f;       // k0/16
    float m2k16 = -2.f * k16;
    unsigned lrow = (unsigned)(lane & 15);
    unsigned grp = (unsigned)(lane >> 4); // k-chunk group 0..3
    unsigned rquad = grp * 4u;
    unsigned kbase = grp * 8u;

    float kjA0 = k16 * sqb[j0A + 0u + lrow];
    float kjA1 = k16 * sqb[j0A + 16u + lrow];
    float kjA2 = k16 * sqb[j0A + 32u + lrow];
    float kjA3 = k16 * sqb[j0A + 48u + lrow];
    float kjB0 = k16 * sqb[j0B + 0u + lrow];
    float kjB1 = k16 * sqb[j0B + 16u + lrow];
    float kjB2 = k16 * sqb[j0B + 32u + lrow];
    float kjB3 = k16 * sqb[j0B + 48u + lrow];

    const short* B0A = ldsB + grp * 512;
    const short* B0B = ldsB + 4096 + grp * 512;
    float eaccA0 = 0.f, eaccA1 = 0.f, eaccB0 = 0.f, eaccB1 = 0.f;

    if (diagA) {
        MMD_PAIR_BODY(true)
    } else {
        MMD_PAIR_BODY(false)
    }

    double acc_d = (double)((eaccA0 + eaccA1) * scaleA) +
                   (double)((eaccB0 + eaccB1) * scaleB);
#pragma unroll
    for (int o = 32; o > 0; o >>= 1) acc_d += __shfl_down(acc_d, o);
    if (lane == 0) pblock[job] = acc_d;
}

// Final reduce: block b sums its batch's 1056 job partials.
__global__ __launch_bounds__(256) void finalize_kernel(const double* __restrict__ pblock,
                                                       float* __restrict__ out) {
    int b = blockIdx.x, t = threadIdx.x;
    const double* p = pblock + (size_t)b * NJOB_PER_BATCH;
    double s = 0.0;
    for (int i = t; i < NJOB_PER_BATCH; i += 256) s += p[i];
#pragma unroll
    for (int o = 32; o > 0; o >>= 1) s += __shfl_down(s, o);
    __shared__ double w[4];
    if ((t & 63) == 0) w[t >> 6] = s;
    __syncthreads();
    if (t == 0)
        out[b] = (float)((w[0] + w[1] + w[2] + w[3]) / ((double)N_HALF * (double)N_HALF));
}

extern "C" void kernel_launch(void* const* d_in, const int* in_sizes, int n_in,
                              void* d_out, int out_size, void* d_ws, size_t ws_size,
                              hipStream_t stream) {
    const float* x = (const float*)d_in[0];
    const float* y = (const float*)d_in[1];
    float* out = (float*)d_out;
    char* ws = (char*)d_ws;

    // pblock aliases colsum_part: colsum dead after bw_kernel, pblock written
    // strictly later in the same stream.
    float*  k0arr       = (float*)ws;                     // [0, 16)
    float*  ssq_part    = (float*)(ws + 4096);            // 1 KB
    float*  colsum_part = (float*)(ws + 8192);            // 64 KB (dies at bw)
    double* pblock      = (double*)(ws + 8192);           // 4224*8 = 33792 B
    float*  sq          = (float*)(ws + 77824);           // 64 KB
    unsigned short* tot_hi = (unsigned short*)(ws + 143360);            // 2 MB
    unsigned short* tot_lo = (unsigned short*)(ws + 143360 + 2097152);  // 2 MB

    prep_kernel<<<256, 256, 0, stream>>>(x, y, tot_hi, tot_lo, sq, ssq_part, colsum_part);
    bw_kernel<<<BATCH, 256, 0, stream>>>(ssq_part, colsum_part, k0arr);
    mmd_mfma<<<NJOB, 64, 0, stream>>>(tot_hi, tot_lo, sq, k0arr, pblock);
    finalize_kernel<<<BATCH, 256, 0, stream>>>(pblock, out);
}

// Round 21
// 44.145 us; speedup vs baseline: 1.6805x; 1.6805x over previous
//
#include <hip/hip_runtime.h>

#define N_TOT 4096
#define N_HALF 2048
#define DIMS 64
#define BATCH 4
#define WGRID 64              // 4096/64 wave-tile rows
#define TRI_PER_BATCH 2080    // 64*65/2 upper-tri 64x64 wave-tiles
#define NWG (BATCH * TRI_PER_BATCH)   // 8320, divisible by 8

typedef __attribute__((ext_vector_type(8))) short short8;
typedef __attribute__((ext_vector_type(4))) float f32x4;

#if __has_builtin(__builtin_amdgcn_exp2f)
#define EXP2F(x) __builtin_amdgcn_exp2f(x)
#else
#define EXP2F(x) exp2f(x)
#endif

__device__ __forceinline__ unsigned short f2bf_rne(float f) {
    unsigned int u = __float_as_uint(f);
    unsigned int r = (u + 0x7FFFu + ((u >> 16) & 1u)) >> 16;
    return (unsigned short)r;
}
__device__ __forceinline__ float bf2f(unsigned short h) {
    return __uint_as_float(((unsigned int)h) << 16);
}

// Prep: fp32 -> bf16 hi/lo split, row sq-norms, per-block partials for Ssq and
// colsum. 256 blocks x 256 thr x 16 floats.
__global__ __launch_bounds__(256) void prep_kernel(const float* __restrict__ x,
                                                   const float* __restrict__ y,
                                                   unsigned short* __restrict__ hi,
                                                   unsigned short* __restrict__ lo,
                                                   float* __restrict__ sq,
                                                   float* __restrict__ ssq_part,
                                                   float* __restrict__ colsum_part) {
    int g = blockIdx.x;
    int t = threadIdx.x;
    bool isx = g < 128;
    int gg = isx ? g : g - 128;
    int base = gg << 12;
    int b = gg >> 5;
    const float* src = isx ? x : y;

    float q_acc = 0.f;
    float4 c_acc = {0.f, 0.f, 0.f, 0.f};
#pragma unroll
    for (int it = 0; it < 4; ++it) {
        int e = base + (it << 10) + (t << 2);
        int rem = e & 131071;
        float4 v = *(const float4*)(src + e);
        unsigned dst = (unsigned)b * 262144u + (isx ? 0u : 131072u) + (unsigned)rem;
        ushort4 h, l;
        h.x = f2bf_rne(v.x); l.x = f2bf_rne(v.x - bf2f(h.x));
        h.y = f2bf_rne(v.y); l.y = f2bf_rne(v.y - bf2f(h.y));
        h.z = f2bf_rne(v.z); l.z = f2bf_rne(v.z - bf2f(h.z));
        h.w = f2bf_rne(v.w); l.w = f2bf_rne(v.w - bf2f(h.w));
        *(ushort4*)(hi + dst) = h;
        *(ushort4*)(lo + dst) = l;

        float p = fmaf(v.x, v.x, fmaf(v.y, v.y, fmaf(v.z, v.z, v.w * v.w)));
        p += __shfl_xor(p, 1);
        p += __shfl_xor(p, 2);
        p += __shfl_xor(p, 4);
        p += __shfl_xor(p, 8);
        int rwi = rem >> 6;
        if ((t & 15) == 0)
            sq[b * N_TOT + (isx ? rwi : N_HALF + rwi)] = p;

        float q = p;
        q += __shfl_xor(q, 16);
        q += __shfl_xor(q, 32);
        q_acc += q;

        float4 c = v;
        c.x += __shfl_xor(c.x, 16); c.y += __shfl_xor(c.y, 16);
        c.z += __shfl_xor(c.z, 16); c.w += __shfl_xor(c.w, 16);
        c.x += __shfl_xor(c.x, 32); c.y += __shfl_xor(c.y, 32);
        c.z += __shfl_xor(c.z, 32); c.w += __shfl_xor(c.w, 32);
        c_acc.x += c.x; c_acc.y += c.y; c_acc.z += c.z; c_acc.w += c.w;
    }

    __shared__ float wsum[4];
    __shared__ float4 csh[4][16];
    int wid = t >> 6;
    if ((t & 63) == 0) wsum[wid] = q_acc;
    if ((t & 63) < 16) csh[wid][t & 63] = c_acc;
    __syncthreads();
    if (t == 0) ssq_part[g] = wsum[0] + wsum[1] + wsum[2] + wsum[3];
    if (t < 16) {
        float4 s0 = csh[0][t], s1 = csh[1][t], s2 = csh[2][t], s3 = csh[3][t];
        float4 o;
        o.x = s0.x + s1.x + s2.x + s3.x;
        o.y = s0.y + s1.y + s2.y + s3.y;
        o.z = s0.z + s1.z + s2.z + s3.z;
        o.w = s0.w + s1.w + s2.w + s3.w;
        *(float4*)(colsum_part + (size_t)g * 64 + t * 4) = o;
    }
}

// Reduce partials -> k0[b]. 4 blocks (one per batch).
__global__ __launch_bounds__(256) void bw_kernel(const float* __restrict__ ssq_part,
                                                 const float* __restrict__ colsum_part,
                                                 float* __restrict__ k0arr) {
    int b = blockIdx.x;
    int t = threadIdx.x;
    int c = t & 63, q = t >> 6;
    float cs = 0.f;
#pragma unroll
    for (int pp = 0; pp < 16; ++pp) {
        int p = q * 16 + pp;
        int g = (p < 32) ? (b * 32 + p) : (128 + b * 32 + (p - 32));
        cs += colsum_part[(size_t)g * 64 + c];
    }
    __shared__ float csq[4][64];
    csq[q][c] = cs;
    __syncthreads();
    if (t < 64) {
        float col = csq[0][t] + csq[1][t] + csq[2][t] + csq[3][t];
        double cc = (double)col * (double)col;
#pragma unroll
        for (int o = 32; o > 0; o >>= 1) cc += __shfl_xor(cc, o);
        int g = (t < 32) ? (b * 32 + t) : (128 + b * 32 + (t - 32));
        double sd = (double)ssq_part[g];
#pragma unroll
        for (int o = 32; o > 0; o >>= 1) sd += __shfl_xor(sd, o);
        if (t == 0) {
            double sumL2 = 2.0 * (double)N_TOT * sd - 2.0 * cc;
            double bw = sumL2 / ((double)N_TOT * (double)N_TOT - (double)N_TOT);
            bw *= 0.25;
            k0arr[b] = (float)(-1.4426950408889634 / bw);
        }
    }
}

// Main: SINGLE-WAVE blocks (64 threads), 64x64 upper-tri wave-tiles, NO
// barriers anywhere. 2-pass MFMA: dot' = (ah+al)*bh = a*bh exactly -> B-lo
// never needed (MFMA -33%, LDS panel 8 KB, LDS reads halve). B-hi staged
// wave-locally; A hi+lo direct from L2 (consecutive tiles share A rows).
// [Session-best structure: r14 = 43.7 us. r15 zero-LDS, r16/r18 diag-hoist,
// r19 4-wave packing, r20 pair-tiles all neutral or regressed; any live-set
// growth trips the single-wave 64-VGPR allocator cap into scratch spill.]
__global__ void mmd_mfma(const unsigned short* __restrict__ hi,
                         const unsigned short* __restrict__ lo,
                         const float* __restrict__ sq,
                         const float* __restrict__ k0arr,
                         double* __restrict__ pblock) {
    // bijective XCD swizzle (NWG % 8 == 0)
    int wg0 = blockIdx.x;
    int wg = (wg0 & 7) * (NWG / 8) + (wg0 >> 3);
    int b = wg / TRI_PER_BATCH;
    int r = wg % TRI_PER_BATCH;
    int ib = 0, cum = 0;
    while (r >= cum + (WGRID - ib)) { cum += WGRID - ib; ++ib; }
    int jb = ib + (r - cum);
    unsigned i0 = (unsigned)ib * 64u;
    unsigned j0 = (unsigned)jb * 64u;
    int lane = threadIdx.x;           // 0..63

    const unsigned short* Hb = hi + (unsigned)b * 262144u;
    const unsigned short* Lb = lo + (unsigned)b * 262144u;
    const float* sqb = sq + b * N_TOT;

    // ---- stage B-hi panel (64 rows x 64 k = 8 KB), [slot8][row64] layout ----
    // shorts index = slot*512 + row*8; slot s holds k-chunk s (8 bf16).
    __shared__ short ldsB[4096];
    {
        unsigned gb = (j0 + (unsigned)lane) * 64u;
#pragma unroll
        for (int k = 0; k < 8; ++k) {
            short8 v = *(const short8*)(Hb + gb + (unsigned)k * 8u);
            *(short8*)(ldsB + k * 512 + lane * 8) = v;
        }
    }
    // no __syncthreads: single wave; compiler orders ds_read after ds_write.

    bool diag = (ib == jb);
    float wsign = ((i0 < (unsigned)N_HALF) == (j0 < (unsigned)N_HALF)) ? 1.f : -1.f;
    float k16 = k0arr[b] * 0.0625f;      // k0/16
    float m2k16 = -2.f * k16;
    unsigned lrow = (unsigned)(lane & 15);
    unsigned grp = (unsigned)(lane >> 4);   // k-chunk group 0..3
    unsigned rquad = grp * 4u;
    unsigned kbase = grp * 8u;

    float kj16[4];
#pragma unroll
    for (int nf = 0; nf < 4; ++nf)
        kj16[nf] = k16 * sqb[j0 + (unsigned)nf * 16u + lrow];

    const short* B0 = ldsB + grp * 512;          // k-half 0 slot base
    float eacc0 = 0.f, eacc1 = 0.f;

#pragma unroll
    for (int mf = 0; mf < 4; ++mf) {
        unsigned ra = (i0 + (unsigned)mf * 16u + lrow) * 64u + kbase;
        short8 ah0 = *(const short8*)(Hb + ra);
        short8 ah1 = *(const short8*)(Hb + ra + 32u);
        short8 al0 = *(const short8*)(Lb + ra);
        short8 al1 = *(const short8*)(Lb + ra + 32u);
        float4 sv = *(const float4*)(sqb + i0 + (unsigned)mf * 16u + rquad);
        float ki[4] = {k16 * sv.x, k16 * sv.y, k16 * sv.z, k16 * sv.w};

#pragma unroll
        for (int nf = 0; nf < 4; ++nf) {
            const short* bp = B0 + (nf * 16 + (int)lrow) * 8;
            short8 bh0 = *(const short8*)(bp);
            short8 bh1 = *(const short8*)(bp + 2048);   // k-half 1 (slot+4)

            // dot = a*bh exactly: (ah + al) x bh via two passes per k-half
            f32x4 accP = (f32x4){0.f, 0.f, 0.f, 0.f};
            f32x4 accQ = (f32x4){0.f, 0.f, 0.f, 0.f};
            accP = __builtin_amdgcn_mfma_f32_16x16x32_bf16(ah0, bh0, accP, 0, 0, 0);
            accQ = __builtin_amdgcn_mfma_f32_16x16x32_bf16(ah1, bh1, accQ, 0, 0, 0);
            accP = __builtin_amdgcn_mfma_f32_16x16x32_bf16(al0, bh0, accP, 0, 0, 0);
            accQ = __builtin_amdgcn_mfma_f32_16x16x32_bf16(al1, bh1, accQ, 0, 0, 0);

#pragma unroll
            for (int rg = 0; rg < 4; ++rg) {
                float t16 = fmaf(m2k16, accQ[rg],
                                 fmaf(m2k16, accP[rg], ki[rg] + kj16[nf]));
                float e4 = EXP2F(t16);       // exp2(t/16)
                float e3 = e4 * e4;          // squaring chain
                float e2 = e3 * e3;
                float e1 = e2 * e2;
                float e0 = e1 * e1;
                float es = ((e0 + e1) + (e2 + e3)) + e4;
                if (diag) {
                    int i = mf * 16 + (int)rquad + rg;
                    int j = nf * 16 + (int)lrow;
                    float w = (j > i) ? 2.f : ((j == i) ? 1.f : 0.f);
                    es *= w;
                }
                if (rg & 1) eacc1 += es; else eacc0 += es;
            }
        }
    }

    double acc_d = (double)((eacc0 + eacc1) * (diag ? wsign : 2.f * wsign));
#pragma unroll
    for (int o = 32; o > 0; o >>= 1) acc_d += __shfl_down(acc_d, o);
    if (lane == 0) pblock[wg] = acc_d;
}

// Final reduce: block b sums its batch's 2080 wave-tile partials.
__global__ __launch_bounds__(256) void finalize_kernel(const double* __restrict__ pblock,
                                                       float* __restrict__ out) {
    int b = blockIdx.x, t = threadIdx.x;
    const double* p = pblock + (size_t)b * TRI_PER_BATCH;
    double s = 0.0;
    for (int i = t; i < TRI_PER_BATCH; i += 256) s += p[i];
#pragma unroll
    for (int o = 32; o > 0; o >>= 1) s += __shfl_down(s, o);
    __shared__ double w[4];
    if ((t & 63) == 0) w[t >> 6] = s;
    __syncthreads();
    if (t == 0)
        out[b] = (float)((w[0] + w[1] + w[2] + w[3]) / ((double)N_HALF * (double)N_HALF));
}

extern "C" void kernel_launch(void* const* d_in, const int* in_sizes, int n_in,
                              void* d_out, int out_size, void* d_ws, size_t ws_size,
                              hipStream_t stream) {
    const float* x = (const float*)d_in[0];
    const float* y = (const float*)d_in[1];
    float* out = (float*)d_out;
    char* ws = (char*)d_ws;

    // pblock aliases the colsum_part region: colsum dead after bw_kernel,
    // pblock written by mmd strictly later in the same stream.
    float*  k0arr       = (float*)ws;                     // [0, 16)
    float*  ssq_part    = (float*)(ws + 4096);            // 1 KB
    float*  colsum_part = (float*)(ws + 8192);            // 64 KB (dies at bw)
    double* pblock      = (double*)(ws + 8192);           // 8320*8 = 66560 B
    float*  sq          = (float*)(ws + 77824);           // 64 KB
    unsigned short* tot_hi = (unsigned short*)(ws + 143360);            // 2 MB
    unsigned short* tot_lo = (unsigned short*)(ws + 143360 + 2097152);  // 2 MB

    prep_kernel<<<256, 256, 0, stream>>>(x, y, tot_hi, tot_lo, sq, ssq_part, colsum_part);
    bw_kernel<<<BATCH, 256, 0, stream>>>(ssq_part, colsum_part, k0arr);
    mmd_mfma<<<NWG, 64, 0, stream>>>(tot_hi, tot_lo, sq, k0arr, pblock);
    finalize_kernel<<<BATCH, 256, 0, stream>>>(pblock, out);
}